// Round 19
// baseline (185.172 us; speedup 1.0000x reference)
//
#include <hip/hip_runtime.h>
#include <math.h>

#define BTOT   32768
#define LAT    128
#define H      17
#define G4     68      // 4*H
#define TSTEPS 50
#define NPR    102     // projection rows: 68 (W_ih) + 17 (W_h0) + 17 (W_c0)
#define WPAD   40      // Wbuf row stride (k-quarter staging, R14-proven)
#define XPAD   132

#define NW     8              // waves per block
#define RPW    4              // rows per wave: 2 sets x 2 rows (34/64 lanes active)
#define RPB    32             // rows per block -> grid = 1024 = 4 blocks/CU exactly
#define TPB    512

// x_tile stride 132: rows r,r+8 alias -> 2-bit XOR key (R13/R14-proven).
#define XSWZ(r, c4)   ((c4) ^ ((((r) >> 3) & 3) << 2))
// Wbuf stride 40: rows r,r+4 alias -> key on bits 2-3 (R14-proven).
#define WSWZ(row, c4) ((c4) ^ ((((row) >> 2) & 3) << 2))

// f32-only gates (R9: recurrence amplifies per-step error ~1e3x; f16 fails).
__device__ __forceinline__ float fsigmoid(float x) {
    float e = __expf(-x);
    return __builtin_amdgcn_rcpf(1.0f + e);
}
// tanh(x) = 1 - 2*rcp(exp(2x)+1); +inf -> 1, -inf -> -1, no divide.
__device__ __forceinline__ float ftanhf(float x) {
    float e = __expf(2.0f * x);
    float t = __builtin_amdgcn_rcpf(e + 1.0f);
    return fmaf(-2.0f, t, 1.0f);
}

#define FMAC(acc, w, h) asm("v_fmac_f32 %0, %1, %2" : "+v"(acc) : "v"(w), "v"(h))

#define FQ(Q, HV) \
    FMAC(ai,Wi[4*Q+0],HV.x); FMAC(af,Wf[4*Q+0],HV.x); FMAC(ag,Wg[4*Q+0],HV.x); FMAC(ao,Wo[4*Q+0],HV.x); \
    FMAC(ai,Wi[4*Q+1],HV.y); FMAC(af,Wf[4*Q+1],HV.y); FMAC(ag,Wg[4*Q+1],HV.y); FMAC(ao,Wo[4*Q+1],HV.y); \
    FMAC(ai,Wi[4*Q+2],HV.z); FMAC(af,Wf[4*Q+2],HV.z); FMAC(ag,Wg[4*Q+2],HV.z); FMAC(ao,Wo[4*Q+2],HV.z); \
    FMAC(ai,Wi[4*Q+3],HV.w); FMAC(af,Wf[4*Q+3],HV.w); FMAC(ag,Wg[4*Q+3],HV.w); FMAC(ao,Wo[4*Q+3],HV.w);

// (512,2): reg cap 256 -> no spill; LDS (40.4KB) is the designed occupancy cap:
// 4 blocks/CU x 8 waves = 32 waves/CU = 8 waves/SIMD, grid exactly co-resident.
__global__ __launch_bounds__(TPB, 2)
void lstm_fused(const float* __restrict__ x,
                const float* __restrict__ W_h0, const float* __restrict__ b_h0,
                const float* __restrict__ W_c0, const float* __restrict__ b_c0,
                const float* __restrict__ W_ih, const float* __restrict__ W_hh,
                const float* __restrict__ b_ih, const float* __restrict__ b_hh,
                float* __restrict__ out)
{
    __shared__ __align__(16) float x_tile[RPB][XPAD];   // 16.9 KB
    __shared__ __align__(16) float Wbuf[NPR][WPAD];     // 16.3 KB (one k-quarter)
    __shared__ __align__(16) float Wl[G4 * H];          //  4.6 KB (W_hh f32)
    __shared__ __align__(16) float hbuf[NW][RPW][20];   //  2.6 KB
    // total 40.4 KB -> exactly 4 blocks/CU; grid 1024 = 4 x 256 (no tail round)

    const int t    = threadIdx.x;
    const int w    = t >> 6;
    const int lane = t & 63;
    const bool active = lane < 2 * H;         // 34 active lanes
    const int rl = active ? (lane / H) : 0;   // 0..1
    const int j  = active ? (lane % H) : 0;   // 0..16
    const int rA = w * RPW + rl;              // set-A block-local row
    const int rB = rA + 2;                    // set-B block-local row
    const int grow0 = blockIdx.x * RPB;
    const int gA = grow0 + rA;                // exact grid: always < BTOT
    const int gB = grow0 + rB;

    // ---- stage x tile + W_hh; all 512 threads ----
    for (int i = t; i < RPB * 32; i += TPB) {              // 1024 float4 = 2 iters
        int rr = i >> 5, c4 = (i & 31) * 4;
        *(float4*)&x_tile[rr][XSWZ(rr, c4)] =
            *(const float4*)(x + (size_t)(grow0 + rr) * LAT + c4);
    }
    for (int i = t; i < G4 * H; i += TPB) Wl[i] = W_hh[i];

    // ---- phase 1: projections for both sets, four k-quarters of 32 ----
    float acc[12];                                         // A: 0-5, B: 6-11
#pragma unroll
    for (int s = 0; s < 12; ++s) acc[s] = 0.0f;
    const int rows6[6] = { j, 17 + j, 34 + j, 51 + j, 68 + j, 85 + j };
    for (int qh = 0; qh < 4; ++qh) {
        __syncthreads();  // qh=0: x_tile/Wl ready; else WAR on Wbuf
        for (int i = t; i < NPR * 8; i += TPB) {           // 8 float4 per quarter-row
            int row = i >> 3, c4 = (i & 7) * 4;
            const float* src = (row < G4) ? (W_ih + row * LAT)
                             : (row < 85) ? (W_h0 + (row - G4) * LAT)
                                          : (W_c0 + (row - 85) * LAT);
            *(float4*)&Wbuf[row][WSWZ(row, c4)] = *(const float4*)(src + qh * 32 + c4);
        }
        __syncthreads();  // quarter ready
        for (int kb = 0; kb < 8; ++kb) {
            const int xc = qh * 32 + kb * 4;
            float4 xa = *(const float4*)&x_tile[rA][XSWZ(rA, xc)];
            float4 xb = *(const float4*)&x_tile[rB][XSWZ(rB, xc)];
#pragma unroll
            for (int p = 0; p < 6; ++p) {
                const int row = rows6[p];
                float4 wv = *(const float4*)&Wbuf[row][WSWZ(row, kb * 4)];
                acc[p]     = fmaf(xa.x, wv.x, acc[p]);
                acc[p]     = fmaf(xa.y, wv.y, acc[p]);
                acc[p]     = fmaf(xa.z, wv.z, acc[p]);
                acc[p]     = fmaf(xa.w, wv.w, acc[p]);
                acc[6 + p] = fmaf(xb.x, wv.x, acc[6 + p]);
                acc[6 + p] = fmaf(xb.y, wv.y, acc[6 + p]);
                acc[6 + p] = fmaf(xb.z, wv.z, acc[6 + p]);
                acc[6 + p] = fmaf(xb.w, wv.w, acc[6 + p]);
            }
        }
    }

    const float bi0 = b_ih[j]      + b_hh[j];
    const float bi1 = b_ih[17 + j] + b_hh[17 + j];
    const float bi2 = b_ih[34 + j] + b_hh[34 + j];
    const float bi3 = b_ih[51 + j] + b_hh[51 + j];
    const float xgAi = acc[0] + bi0, xgAf = acc[1] + bi1;
    const float xgAg = acc[2] + bi2, xgAo = acc[3] + bi3;
    const float xgBi = acc[6] + bi0, xgBf = acc[7] + bi1;
    const float xgBg = acc[8] + bi2, xgBo = acc[9] + bi3;
    float hA = acc[4]  + b_h0[j], cA = acc[5]  + b_c0[j];
    float hB = acc[10] + b_h0[j], cB = acc[11] + b_c0[j];

    // ---- W_hh rows for gates i,f,g,o of element j -> registers ----
    float Wi[H], Wf[H], Wg[H], Wo[H];
#pragma unroll
    for (int k = 0; k < H; ++k) {
        Wi[k] = Wl[(0 * H + j) * H + k];
        Wf[k] = Wl[(1 * H + j) * H + k];
        Wg[k] = Wl[(2 * H + j) * H + k];
        Wo[k] = Wl[(3 * H + j) * H + k];
        asm volatile("" : "+v"(Wi[k]), "+v"(Wf[k]), "+v"(Wg[k]), "+v"(Wo[k]));
    }

    // ---- phase 2: R13 depth-2 A/B pipeline, zero barriers ----
    float* orowA = out + (size_t)gA * (TSTEPS * H) + j;
    float* orowB = out + (size_t)gB * (TSTEPS * H) + j;
    const float* hbA = &hbuf[w][rl][0];
    const float* hbB = &hbuf[w][2 + rl][0];

    // prologue: A's step-0 exchange
    if (active) hbuf[w][rl][j] = hA;
    float4 a0 = *(const float4*)&hbA[0];
    float4 a1 = *(const float4*)&hbA[4];
    float4 a2 = *(const float4*)&hbA[8];
    float4 a3 = *(const float4*)&hbA[12];
    float  a4 = hbA[16];

    for (int tt = 0; tt < TSTEPS; ++tt) {
        // --- B exchange for this step (consumed after A's compute) ---
        if (active) hbuf[w][2 + rl][j] = hB;
        float4 b0 = *(const float4*)&hbB[0];
        float4 b1 = *(const float4*)&hbB[4];
        float4 b2 = *(const float4*)&hbB[8];
        float4 b3 = *(const float4*)&hbB[12];
        float  b4 = hbB[16];

        // --- A compute (frag loaded last iteration / prologue) ---
        {
            float ai = xgAi, af = xgAf, ag = xgAg, ao = xgAo;
            FQ(0, a0) FQ(1, a1) FQ(2, a2) FQ(3, a3)
            FMAC(ai, Wi[16], a4); FMAC(af, Wf[16], a4);
            FMAC(ag, Wg[16], a4); FMAC(ao, Wo[16], a4);
            const float ig = fsigmoid(ai), fg = fsigmoid(af);
            const float gv = ftanhf(ag),  og = fsigmoid(ao);
            cA = fmaf(fg, cA, ig * gv);
            hA = og * ftanhf(cA);
        }

        // --- A exchange for NEXT step (hidden under B's compute) ---
        if (active) hbuf[w][rl][j] = hA;
        a0 = *(const float4*)&hbA[0];
        a1 = *(const float4*)&hbA[4];
        a2 = *(const float4*)&hbA[8];
        a3 = *(const float4*)&hbA[12];
        a4 = hbA[16];

        // --- B compute ---
        {
            float ai = xgBi, af = xgBf, ag = xgBg, ao = xgBo;
            FQ(0, b0) FQ(1, b1) FQ(2, b2) FQ(3, b3)
            FMAC(ai, Wi[16], b4); FMAC(af, Wf[16], b4);
            FMAC(ag, Wg[16], b4); FMAC(ao, Wo[16], b4);
            const float ig = fsigmoid(ai), fg = fsigmoid(af);
            const float gv = ftanhf(ag),  og = fsigmoid(ao);
            cB = fmaf(fg, cB, ig * gv);
            hB = og * ftanhf(cB);
        }

        // --- stores (async vmem, off the critical path) ---
        if (active) orowA[tt * H] = hA;
        if (active) orowB[tt * H] = hB;
    }
}

extern "C" void kernel_launch(void* const* d_in, const int* in_sizes, int n_in,
                              void* d_out, int out_size, void* d_ws, size_t ws_size,
                              hipStream_t stream)
{
    const float* x    = (const float*)d_in[0];
    const float* W_h0 = (const float*)d_in[1];
    const float* b_h0 = (const float*)d_in[2];
    const float* W_c0 = (const float*)d_in[3];
    const float* b_c0 = (const float*)d_in[4];
    const float* W_ih = (const float*)d_in[5];
    const float* W_hh = (const float*)d_in[6];
    const float* b_ih = (const float*)d_in[7];
    const float* b_hh = (const float*)d_in[8];
    float* out = (float*)d_out;

    (void)d_ws; (void)ws_size;  // no workspace used

    const int nblk = BTOT / RPB;   // 1024 exactly
    hipLaunchKernelGGL(lstm_fused, dim3(nblk), dim3(TPB), 0, stream,
                       x, W_h0, b_h0, W_c0, b_c0, W_ih, W_hh, b_ih, b_hh, out);
}

// Round 20
// 130.771 us; speedup vs baseline: 1.4160x; 1.4160x over previous
//
#include <hip/hip_runtime.h>
#include <math.h>

#define BTOT   32768
#define LAT    128
#define H      17
#define G4     68      // 4*H
#define TSTEPS 50
#define NPR    102     // projection rows: 68 (W_ih) + 17 (W_h0) + 17 (W_c0)
#define WPAD   40      // Wbuf row stride (k-quarter staging, R14-proven)
#define XPAD   132

#define NW     4              // waves per block (small blocks -> decorrelated)
#define RPB    12             // 3 rows per wave, 51/64 lanes active
#define TPB    256

// x_tile stride 132: rows r,r+8 alias -> 2-bit XOR key (R13/R14-proven).
#define XSWZ(r, c4)   ((c4) ^ ((((r) >> 3) & 3) << 2))
// Wbuf stride 40: rows r,r+4 alias -> key on bits 2-3 (R14-proven).
#define WSWZ(row, c4) ((c4) ^ ((((row) >> 2) & 3) << 2))

// f32-only gates (R9: recurrence amplifies per-step error ~1e3x; f16 fails).
__device__ __forceinline__ float fsigmoid(float x) {
    float e = __expf(-x);
    return __builtin_amdgcn_rcpf(1.0f + e);
}
// tanh(x) = 1 - 2*rcp(exp(2x)+1); +inf -> 1, -inf -> -1, no divide.
__device__ __forceinline__ float ftanhf(float x) {
    float e = __expf(2.0f * x);
    float t = __builtin_amdgcn_rcpf(e + 1.0f);
    return fmaf(-2.0f, t, 1.0f);
}

#define FMAC(acc, w, h) asm("v_fmac_f32 %0, %1, %2" : "+v"(acc) : "v"(w), "v"(h))

#define FQ(Q, HV) \
    FMAC(ai,Wi[4*Q+0],HV.x); FMAC(af,Wf[4*Q+0],HV.x); FMAC(ag,Wg[4*Q+0],HV.x); FMAC(ao,Wo[4*Q+0],HV.x); \
    FMAC(ai,Wi[4*Q+1],HV.y); FMAC(af,Wf[4*Q+1],HV.y); FMAC(ag,Wg[4*Q+1],HV.y); FMAC(ao,Wo[4*Q+1],HV.y); \
    FMAC(ai,Wi[4*Q+2],HV.z); FMAC(af,Wf[4*Q+2],HV.z); FMAC(ag,Wg[4*Q+2],HV.z); FMAC(ao,Wo[4*Q+2],HV.z); \
    FMAC(ai,Wi[4*Q+3],HV.w); FMAC(af,Wf[4*Q+3],HV.w); FMAC(ag,Wg[4*Q+3],HV.w); FMAC(ao,Wo[4*Q+3],HV.w);

// (256,4): 4 waves/EU minimum -> unified reg cap 128. Single row-set per wave
// (W 68 + state ~40 = ~110) fits under the cap WITHOUT spill (R10 precedent:
// cap 102 fit and raised occupancy to 38%). 4 blocks/CU x 4 waves = 16 waves/CU,
// blocks at different T-phases -> decorrelated stalls, TLP hides the chain.
__global__ __launch_bounds__(TPB, 4)
void lstm_fused(const float* __restrict__ x,
                const float* __restrict__ W_h0, const float* __restrict__ b_h0,
                const float* __restrict__ W_c0, const float* __restrict__ b_c0,
                const float* __restrict__ W_ih, const float* __restrict__ W_hh,
                const float* __restrict__ b_ih, const float* __restrict__ b_hh,
                float* __restrict__ out)
{
    __shared__ __align__(16) float x_tile[RPB][XPAD];   //  6.3 KB
    __shared__ __align__(16) float Wbuf[NPR][WPAD];     // 16.3 KB (one k-quarter)
    __shared__ __align__(16) float Wl[G4 * H];          //  4.6 KB (W_hh f32)
    __shared__ __align__(16) float hbuf[NW][3][20];     //  1.0 KB
    // total 28.2 KB -> LDS allows >4 blocks/CU; occupancy capped by regs at 4.

    const int t    = threadIdx.x;
    const int w    = t >> 6;
    const int lane = t & 63;
    const bool active = lane < 3 * H;         // 51
    const int rl = active ? (lane / H) : 0;   // 0..2
    const int j  = active ? (lane % H) : 0;   // 0..16
    const int r0 = w * 3 + rl;                // block-local row 0..11
    const int grow0 = blockIdx.x * RPB;
    int grow = grow0 + r0;
    const bool valid = active && (grow < BTOT);
    if (grow >= BTOT) grow = BTOT - 1;

    // ---- stage x tile (rows clamped) + W_hh; all 256 threads ----
    for (int i = t; i < RPB * 32; i += TPB) {              // 384 float4
        int rr = i >> 5, c4 = (i & 31) * 4;
        int gr = grow0 + rr; if (gr >= BTOT) gr = BTOT - 1;
        *(float4*)&x_tile[rr][XSWZ(rr, c4)] = *(const float4*)(x + (size_t)gr * LAT + c4);
    }
    for (int i = t; i < G4 * H; i += TPB) Wl[i] = W_hh[i];

    // ---- phase 1: projections, four k-quarters of 32 (R14-proven layout) ----
    float acc[6] = {0.f, 0.f, 0.f, 0.f, 0.f, 0.f};         // i,f,g,o, h0, c0
    const int rows6[6] = { j, 17 + j, 34 + j, 51 + j, 68 + j, 85 + j };
    for (int qh = 0; qh < 4; ++qh) {
        __syncthreads();  // qh=0: x_tile/Wl ready; else WAR on Wbuf
        for (int i = t; i < NPR * 8; i += TPB) {           // 8 float4 per quarter-row
            int row = i >> 3, c4 = (i & 7) * 4;
            const float* src = (row < G4) ? (W_ih + row * LAT)
                             : (row < 85) ? (W_h0 + (row - G4) * LAT)
                                          : (W_c0 + (row - 85) * LAT);
            *(float4*)&Wbuf[row][WSWZ(row, c4)] = *(const float4*)(src + qh * 32 + c4);
        }
        __syncthreads();  // quarter ready
        for (int kb = 0; kb < 8; ++kb) {
            const int xc = qh * 32 + kb * 4;
            float4 xv = *(const float4*)&x_tile[r0][XSWZ(r0, xc)];
#pragma unroll
            for (int p = 0; p < 6; ++p) {
                const int row = rows6[p];
                float4 wv = *(const float4*)&Wbuf[row][WSWZ(row, kb * 4)];
                acc[p] = fmaf(xv.x, wv.x, acc[p]);
                acc[p] = fmaf(xv.y, wv.y, acc[p]);
                acc[p] = fmaf(xv.z, wv.z, acc[p]);
                acc[p] = fmaf(xv.w, wv.w, acc[p]);
            }
        }
    }

    const float xgi = acc[0] + b_ih[j]      + b_hh[j];
    const float xgf = acc[1] + b_ih[17 + j] + b_hh[17 + j];
    const float xgg = acc[2] + b_ih[34 + j] + b_hh[34 + j];
    const float xgo = acc[3] + b_ih[51 + j] + b_hh[51 + j];
    float h = acc[4] + b_h0[j];
    float c = acc[5] + b_c0[j];

    // ---- W_hh rows for gates i,f,g,o of element j -> registers ----
    float Wi[H], Wf[H], Wg[H], Wo[H];
#pragma unroll
    for (int k = 0; k < H; ++k) {
        Wi[k] = Wl[(0 * H + j) * H + k];
        Wf[k] = Wl[(1 * H + j) * H + k];
        Wg[k] = Wl[(2 * H + j) * H + k];
        Wo[k] = Wl[(3 * H + j) * H + k];
        asm volatile("" : "+v"(Wi[k]), "+v"(Wf[k]), "+v"(Wg[k]), "+v"(Wo[k]));
    }

    // ---- phase 2: single-set recurrence, zero barriers (rows wave-local) ----
    // Latency hiding comes from TLP: 16 waves/CU from 4 independent blocks.
    const float* hb = &hbuf[w][rl][0];
    float* orow = out + (size_t)grow * (TSTEPS * H) + j;

    for (int tt = 0; tt < TSTEPS; ++tt) {
        if (active) hbuf[w][rl][j] = h;
        // same-wave write->read on hbuf: compiler inserts lgkmcnt wait

        float4 f0 = *(const float4*)&hb[0];
        float4 f1 = *(const float4*)&hb[4];
        float4 f2 = *(const float4*)&hb[8];
        float4 f3 = *(const float4*)&hb[12];
        float  f4 = hb[16];

        float ai = xgi, af = xgf, ag = xgg, ao = xgo;
        FQ(0, f0) FQ(1, f1) FQ(2, f2) FQ(3, f3)
        FMAC(ai, Wi[16], f4); FMAC(af, Wf[16], f4);
        FMAC(ag, Wg[16], f4); FMAC(ao, Wo[16], f4);

        const float ig = fsigmoid(ai), fg = fsigmoid(af);
        const float gv = ftanhf(ag),  og = fsigmoid(ao);
        c = fmaf(fg, c, ig * gv);
        h = og * ftanhf(c);

        if (valid) orow[tt * H] = h;
    }
}

extern "C" void kernel_launch(void* const* d_in, const int* in_sizes, int n_in,
                              void* d_out, int out_size, void* d_ws, size_t ws_size,
                              hipStream_t stream)
{
    const float* x    = (const float*)d_in[0];
    const float* W_h0 = (const float*)d_in[1];
    const float* b_h0 = (const float*)d_in[2];
    const float* W_c0 = (const float*)d_in[3];
    const float* b_c0 = (const float*)d_in[4];
    const float* W_ih = (const float*)d_in[5];
    const float* W_hh = (const float*)d_in[6];
    const float* b_ih = (const float*)d_in[7];
    const float* b_hh = (const float*)d_in[8];
    float* out = (float*)d_out;

    (void)d_ws; (void)ws_size;  // no workspace used

    const int nblk = (BTOT + RPB - 1) / RPB;   // 2731
    hipLaunchKernelGGL(lstm_fused, dim3(nblk), dim3(TPB), 0, stream,
                       x, W_h0, b_h0, W_c0, b_c0, W_ih, W_hh, b_ih, b_hh, out);
}